// Round 1
// baseline (3866.851 us; speedup 1.0000x reference)
//
#include <hip/hip_runtime.h>
#include <math.h>

#define B_ 512
#define C_ 200
#define D_ 512
#define E_ 256
#define V_ 8192
#define G_ 2048
#define L_ 16

// GEMM tiling: 64x64 tile, BK=32, 256 threads, 4x4 per thread
#define BM 64
#define BN 64
#define BK 32

__device__ __forceinline__ float sigm(float x) { return 1.0f / (1.0f + expf(-x)); }

// ---------------------------------------------------------------------------
// init: h0 = c0 = mean over valid context rows; tok0 = 1
// ---------------------------------------------------------------------------
__global__ __launch_bounds__(256) void k_init(const float* __restrict__ ctx,
                                              const int* __restrict__ counts,
                                              float* __restrict__ h,
                                              float* __restrict__ c,
                                              int* __restrict__ tok) {
    int b = blockIdx.x;
    int t = threadIdx.x;
    int cnt = counts[b];
    const float* base = ctx + (size_t)b * C_ * D_;
    float s0 = 0.f, s1 = 0.f;
    for (int cc = 0; cc < cnt; ++cc) {
        s0 += base[(size_t)cc * D_ + t];
        s1 += base[(size_t)cc * D_ + t + 256];
    }
    float inv = 1.0f / (float)cnt;
    float v0 = s0 * inv, v1 = s1 * inv;
    h[b * D_ + t] = v0;        h[b * D_ + t + 256] = v1;
    c[b * D_ + t] = v0;        c[b * D_ + t + 256] = v1;
    if (t == 0) tok[b] = 1;
}

// ---------------------------------------------------------------------------
// q = h @ W_attn^T   (M=512, N=512, K=512); A,B both row-major K-innermost
// ---------------------------------------------------------------------------
__global__ __launch_bounds__(256) void k_qproj(const float* __restrict__ A,
                                               const float* __restrict__ Bw,
                                               float* __restrict__ Cq) {
    __shared__ float As[BK][BM + 4];
    __shared__ float Bs[BK][BN + 4];
    int t = threadIdx.x;
    int m0 = blockIdx.y * BM;
    int n0 = blockIdx.x * BN;
    int tm = (t & 15) * 4;
    int tn = (t >> 4) * 4;
    float acc[4][4] = {};
    for (int kt = 0; kt < D_; kt += BK) {
        __syncthreads();
        for (int li = t; li < 512; li += 256) {
            int row = li >> 3, c4 = (li & 7) * 4;
            float4 av = *(const float4*)&A[(size_t)(m0 + row) * D_ + kt + c4];
            As[c4 + 0][row] = av.x; As[c4 + 1][row] = av.y;
            As[c4 + 2][row] = av.z; As[c4 + 3][row] = av.w;
            float4 bv = *(const float4*)&Bw[(size_t)(n0 + row) * D_ + kt + c4];
            Bs[c4 + 0][row] = bv.x; Bs[c4 + 1][row] = bv.y;
            Bs[c4 + 2][row] = bv.z; Bs[c4 + 3][row] = bv.w;
        }
        __syncthreads();
#pragma unroll
        for (int k = 0; k < BK; ++k) {
            float4 af = *(const float4*)&As[k][tm];
            float4 bf = *(const float4*)&Bs[k][tn];
            float a[4] = {af.x, af.y, af.z, af.w};
            float bb[4] = {bf.x, bf.y, bf.z, bf.w};
#pragma unroll
            for (int i = 0; i < 4; ++i)
#pragma unroll
                for (int j = 0; j < 4; ++j) acc[i][j] += a[i] * bb[j];
        }
    }
#pragma unroll
    for (int i = 0; i < 4; ++i)
#pragma unroll
        for (int j = 0; j < 4; ++j)
            Cq[(size_t)(m0 + tm + i) * D_ + n0 + tn + j] = acc[i][j];
}

// ---------------------------------------------------------------------------
// attention: one block per batch row. scores -> softmax -> weighted sum
// ---------------------------------------------------------------------------
__global__ __launch_bounds__(256) void k_attn(const float* __restrict__ ctx,
                                              const int* __restrict__ counts,
                                              const float* __restrict__ q,
                                              float* __restrict__ ctxv) {
    __shared__ float w_lds[C_];
    __shared__ float redm[4];
    __shared__ float reds[4];
    int b = blockIdx.x;
    int t = threadIdx.x;
    int lane = t & 63;
    int wv = t >> 6;
    int cnt = counts[b];
    const float* cb = ctx + (size_t)b * C_ * D_;

    // q fragment in registers: dims lane*4..+3 and lane*4+256..+3
    float4 q0 = *(const float4*)&q[(size_t)b * D_ + lane * 4];
    float4 q1 = *(const float4*)&q[(size_t)b * D_ + lane * 4 + 256];

    // phase A: scores (wave w handles rows w, w+4, ...)
    for (int cc = wv; cc < cnt; cc += 4) {
        const float* row = cb + (size_t)cc * D_;
        float4 x0 = *(const float4*)&row[lane * 4];
        float4 x1 = *(const float4*)&row[lane * 4 + 256];
        float s = x0.x * q0.x + x0.y * q0.y + x0.z * q0.z + x0.w * q0.w +
                  x1.x * q1.x + x1.y * q1.y + x1.z * q1.z + x1.w * q1.w;
#pragma unroll
        for (int off = 32; off; off >>= 1) s += __shfl_down(s, off);
        if (lane == 0) w_lds[cc] = s;
    }
    __syncthreads();

    // phase B: softmax over cnt scores
    float sv = (t < cnt) ? w_lds[t] : -INFINITY;
    float m = sv;
#pragma unroll
    for (int off = 32; off; off >>= 1) m = fmaxf(m, __shfl_xor(m, off));
    if (lane == 0) redm[wv] = m;
    __syncthreads();
    m = fmaxf(fmaxf(redm[0], redm[1]), fmaxf(redm[2], redm[3]));
    float e = (t < cnt) ? expf(sv - m) : 0.0f;
    float ps = e;
#pragma unroll
    for (int off = 32; off; off >>= 1) ps += __shfl_xor(ps, off);
    if (lane == 0) reds[wv] = ps;
    if (t < cnt) w_lds[t] = e;
    __syncthreads();
    float inv = 1.0f / (reds[0] + reds[1] + reds[2] + reds[3]);

    // phase C: weighted sum, thread t owns dims t and t+256
    float a0 = 0.f, a1 = 0.f;
    for (int cc = 0; cc < cnt; ++cc) {
        float wc = w_lds[cc];
        a0 += wc * cb[(size_t)cc * D_ + t];
        a1 += wc * cb[(size_t)cc * D_ + t + 256];
    }
    ctxv[(size_t)b * D_ + t] = a0 * inv;
    ctxv[(size_t)b * D_ + t + 256] = a1 * inv;
}

// ---------------------------------------------------------------------------
// gates GEMM + fused LSTM cell.
// A[b,k]: k<256 -> emb_table[tok[b]][k]; k<768 -> ctxv[b,k-256]; else h_in[b,k-768]
// B rows reordered: r = d*4+gate, orig row go = gate*512+d  (gate order i,f,g,o)
// epilogue: each thread owns 4 batches x 1 d (cols = 4 gates of d)
// ---------------------------------------------------------------------------
__global__ __launch_bounds__(256) void k_gates(const int* __restrict__ tok,
                                               const float* __restrict__ emb,
                                               const float* __restrict__ ctxv,
                                               const float* __restrict__ h_in,
                                               const float* __restrict__ W_ih,
                                               const float* __restrict__ b_ih,
                                               const float* __restrict__ W_hh,
                                               const float* __restrict__ b_hh,
                                               float* __restrict__ cbuf,
                                               float* __restrict__ h_out) {
    __shared__ float As[BK][BM + 4];
    __shared__ float Bs[BK][BN + 4];
    int t = threadIdx.x;
    int m0 = blockIdx.y * BM;
    int n0 = blockIdx.x * BN;
    int tm = (t & 15) * 4;
    int tn = (t >> 4) * 4;
    float acc[4][4] = {};
    for (int kt = 0; kt < 1280; kt += BK) {
        __syncthreads();
        for (int li = t; li < 512; li += 256) {
            int row = li >> 3, c4 = (li & 7) * 4;
            int gb = m0 + row;
            float4 av;
            if (kt < 256) {
                int tk = tok[gb];
                av = *(const float4*)&emb[(size_t)tk * E_ + kt + c4];
            } else if (kt < 768) {
                av = *(const float4*)&ctxv[(size_t)gb * D_ + kt - 256 + c4];
            } else {
                av = *(const float4*)&h_in[(size_t)gb * D_ + kt - 768 + c4];
            }
            As[c4 + 0][row] = av.x; As[c4 + 1][row] = av.y;
            As[c4 + 2][row] = av.z; As[c4 + 3][row] = av.w;
            int r = n0 + row;
            int go = ((r & 3) << 9) + (r >> 2);
            float4 bv;
            if (kt < 768) {
                bv = *(const float4*)&W_ih[(size_t)go * 768 + kt + c4];
            } else {
                bv = *(const float4*)&W_hh[(size_t)go * D_ + kt - 768 + c4];
            }
            Bs[c4 + 0][row] = bv.x; Bs[c4 + 1][row] = bv.y;
            Bs[c4 + 2][row] = bv.z; Bs[c4 + 3][row] = bv.w;
        }
        __syncthreads();
#pragma unroll
        for (int k = 0; k < BK; ++k) {
            float4 af = *(const float4*)&As[k][tm];
            float4 bf = *(const float4*)&Bs[k][tn];
            float a[4] = {af.x, af.y, af.z, af.w};
            float bb[4] = {bf.x, bf.y, bf.z, bf.w};
#pragma unroll
            for (int i = 0; i < 4; ++i)
#pragma unroll
                for (int j = 0; j < 4; ++j) acc[i][j] += a[i] * bb[j];
        }
    }
    // fused LSTM epilogue
    int d = (n0 + tn) >> 2;  // the 4 columns are gates i,f,g,o of this d
    float bi = b_ih[d] + b_hh[d];
    float bf_ = b_ih[512 + d] + b_hh[512 + d];
    float bg = b_ih[1024 + d] + b_hh[1024 + d];
    float bo = b_ih[1536 + d] + b_hh[1536 + d];
#pragma unroll
    for (int i = 0; i < 4; ++i) {
        int b = m0 + tm + i;
        float ig = sigm(acc[i][0] + bi);
        float fg = sigm(acc[i][1] + bf_);
        float gg = tanhf(acc[i][2] + bg);
        float og = sigm(acc[i][3] + bo);
        float cn = fg * cbuf[(size_t)b * D_ + d] + ig * gg;
        cbuf[(size_t)b * D_ + d] = cn;
        h_out[(size_t)b * D_ + d] = og * tanhf(cn);
    }
}

// ---------------------------------------------------------------------------
// logits = h @ W_proj^T + b_proj  (M=512, N=8192, K=512), write to out slab
// ---------------------------------------------------------------------------
__global__ __launch_bounds__(256) void k_logits(const float* __restrict__ A,
                                                const float* __restrict__ Bw,
                                                const float* __restrict__ bias,
                                                float* __restrict__ Co) {
    __shared__ float As[BK][BM + 4];
    __shared__ float Bs[BK][BN + 4];
    int t = threadIdx.x;
    int m0 = blockIdx.y * BM;
    int n0 = blockIdx.x * BN;
    int tm = (t & 15) * 4;
    int tn = (t >> 4) * 4;
    float acc[4][4] = {};
    for (int kt = 0; kt < D_; kt += BK) {
        __syncthreads();
        for (int li = t; li < 512; li += 256) {
            int row = li >> 3, c4 = (li & 7) * 4;
            float4 av = *(const float4*)&A[(size_t)(m0 + row) * D_ + kt + c4];
            As[c4 + 0][row] = av.x; As[c4 + 1][row] = av.y;
            As[c4 + 2][row] = av.z; As[c4 + 3][row] = av.w;
            float4 bv = *(const float4*)&Bw[(size_t)(n0 + row) * D_ + kt + c4];
            Bs[c4 + 0][row] = bv.x; Bs[c4 + 1][row] = bv.y;
            Bs[c4 + 2][row] = bv.z; Bs[c4 + 3][row] = bv.w;
        }
        __syncthreads();
#pragma unroll
        for (int k = 0; k < BK; ++k) {
            float4 af = *(const float4*)&As[k][tm];
            float4 bf = *(const float4*)&Bs[k][tn];
            float a[4] = {af.x, af.y, af.z, af.w};
            float bb[4] = {bf.x, bf.y, bf.z, bf.w};
#pragma unroll
            for (int i = 0; i < 4; ++i)
#pragma unroll
                for (int j = 0; j < 4; ++j) acc[i][j] += a[i] * bb[j];
        }
    }
#pragma unroll
    for (int j = 0; j < 4; ++j) {
        float bj = bias[n0 + tn + j];
#pragma unroll
        for (int i = 0; i < 4; ++i)
            Co[(size_t)(m0 + tm + i) * V_ + n0 + tn + j] = acc[i][j] + bj;
    }
}

// ---------------------------------------------------------------------------
// argmax over V per batch row; first-index tie-break (matches jnp.argmax)
// ---------------------------------------------------------------------------
__global__ __launch_bounds__(256) void k_argmax(const float* __restrict__ logits,
                                                int* __restrict__ tok) {
    __shared__ float rv[4];
    __shared__ int ri[4];
    int b = blockIdx.x;
    int t = threadIdx.x;
    int lane = t & 63;
    int wv = t >> 6;
    const float* p = logits + (size_t)b * V_;
    float best = -INFINITY;
    int bi = 0x7fffffff;
    for (int v = t; v < V_; v += 256) {
        float x = p[v];
        if (x > best) { best = x; bi = v; }
    }
#pragma unroll
    for (int off = 32; off; off >>= 1) {
        float ov = __shfl_down(best, off);
        int oi = __shfl_down(bi, off);
        if (ov > best || (ov == best && oi < bi)) { best = ov; bi = oi; }
    }
    if (lane == 0) { rv[wv] = best; ri[wv] = bi; }
    __syncthreads();
    if (t == 0) {
        for (int w = 1; w < 4; ++w) {
            if (rv[w] > best || (rv[w] == best && ri[w] < bi)) { best = rv[w]; bi = ri[w]; }
        }
        tok[b] = bi;
    }
}

// ---------------------------------------------------------------------------
extern "C" void kernel_launch(void* const* d_in, const int* in_sizes, int n_in,
                              void* d_out, int out_size, void* d_ws, size_t ws_size,
                              hipStream_t stream) {
    const float* ctx    = (const float*)d_in[0];
    const int*   counts = (const int*)d_in[1];
    // d_in[2] = output_length (scalar 16, hardcoded)
    const float* emb    = (const float*)d_in[3];
    const float* W_attn = (const float*)d_in[4];
    const float* W_ih   = (const float*)d_in[5];
    const float* b_ih   = (const float*)d_in[6];
    const float* W_hh   = (const float*)d_in[7];
    const float* b_hh   = (const float*)d_in[8];
    const float* W_proj = (const float*)d_in[9];
    const float* b_proj = (const float*)d_in[10];
    float* out = (float*)d_out;

    float* hA   = (float*)d_ws;          // [B,D]
    float* hB   = hA + B_ * D_;          // [B,D]
    float* cbuf = hB + B_ * D_;          // [B,D]
    float* qbuf = cbuf + B_ * D_;        // [B,D]
    float* ctxv = qbuf + B_ * D_;        // [B,D]
    int*   tok  = (int*)(ctxv + B_ * D_);  // [B]

    // output slab 0 must be zeros (harness poisons d_out before timing)
    hipMemsetAsync(out, 0, (size_t)B_ * V_ * sizeof(float), stream);

    k_init<<<B_, 256, 0, stream>>>(ctx, counts, hA, cbuf, tok);

    float* hin = hA;
    float* hout = hB;
    for (int t = 1; t < L_; ++t) {
        k_qproj<<<dim3(D_ / BN, B_ / BM), 256, 0, stream>>>(hin, W_attn, qbuf);
        k_attn<<<B_, 256, 0, stream>>>(ctx, counts, qbuf, ctxv);
        k_gates<<<dim3(G_ / BN, B_ / BM), 256, 0, stream>>>(tok, emb, ctxv, hin,
                                                            W_ih, b_ih, W_hh, b_hh,
                                                            cbuf, hout);
        float* slab = out + (size_t)t * B_ * V_;
        k_logits<<<dim3(V_ / BN, B_ / BM), 256, 0, stream>>>(hout, W_proj, b_proj, slab);
        if (t < L_ - 1) k_argmax<<<B_, 256, 0, stream>>>(slab, tok);
        float* tmp = hin; hin = hout; hout = tmp;
    }
}